// Round 11
// baseline (505.107 us; speedup 1.0000x reference)
//
#include <hip/hip_runtime.h>

#define EPS 1e-5f

typedef __attribute__((ext_vector_type(8))) short bf16x8;
typedef __attribute__((ext_vector_type(4))) float f32x4;

// Split f32 -> bf16 hi (truncated) + bf16 lo (residual, truncated).
static __device__ __forceinline__ void split8(float4 f0, float4 f1, bf16x8& hi, bf16x8& lo) {
    float f[8] = {f0.x, f0.y, f0.z, f0.w, f1.x, f1.y, f1.z, f1.w};
    bf16x8 h, l;
#pragma unroll
    for (int i = 0; i < 8; ++i) {
        unsigned u = __float_as_uint(f[i]);
        h[i] = (short)(u >> 16);
        float r = f[i] - __uint_as_float(u & 0xffff0000u);
        l[i] = (short)(__float_as_uint(r) >> 16);
    }
    hi = h; lo = l;
}

static __device__ __forceinline__ float4 bnrelu4(float4 v, float4 a, float4 d) {
    float4 r;
    r.x = fmaxf(a.x * v.x + d.x, 0.f);
    r.y = fmaxf(a.y * v.y + d.y, 0.f);
    r.z = fmaxf(a.z * v.z + d.z, 0.f);
    r.w = fmaxf(a.w * v.w + d.w, 0.f);
    return r;
}

// ================= CSR build =================
__global__ __launch_bounds__(256) void hist_kernel(
    const int* __restrict__ ei, int* __restrict__ deg, int E)
{
    int e = blockIdx.x * 256 + threadIdx.x;
    if (e >= E) return;
    atomicAdd(&deg[ei[E + e]], 1);
}

__global__ __launch_bounds__(256) void blocksum_kernel(
    const int* __restrict__ deg, int* __restrict__ bsum, int N)
{
    int i = blockIdx.x * 256 + threadIdx.x;
    int v = (i < N) ? deg[i] : 0;
#pragma unroll
    for (int o = 1; o < 64; o <<= 1) v += __shfl_xor(v, o);
    __shared__ int s[4];
    if ((threadIdx.x & 63) == 0) s[threadIdx.x >> 6] = v;
    __syncthreads();
    if (threadIdx.x == 0) bsum[blockIdx.x] = s[0] + s[1] + s[2] + s[3];
}

__global__ __launch_bounds__(512) void scanb_kernel(int* bsum, int NB)
{
    __shared__ int sh[512];
    int t = threadIdx.x;
    int v = (t < NB) ? bsum[t] : 0;
    sh[t] = v;
    __syncthreads();
    for (int o = 1; o < 512; o <<= 1) {
        int add = (t >= o) ? sh[t - o] : 0;
        __syncthreads();
        sh[t] += add;
        __syncthreads();
    }
    if (t < NB) bsum[t] = (t == 0) ? 0 : sh[t - 1];
}

__global__ __launch_bounds__(256) void scanfinal_kernel(
    const int* __restrict__ deg, const int* __restrict__ bsum,
    int* __restrict__ rowptr, int* __restrict__ cursor, int N)
{
    int b = blockIdx.x, t = threadIdx.x;
    int i = b * 256 + t;
    int v = (i < N) ? deg[i] : 0;
    __shared__ int sh[256];
    sh[t] = v;
    __syncthreads();
    for (int o = 1; o < 256; o <<= 1) {
        int add = (t >= o) ? sh[t - o] : 0;
        __syncthreads();
        sh[t] += add;
        __syncthreads();
    }
    int excl = sh[t] - v;
    if (i < N) {
        int rp = bsum[b] + excl;
        rowptr[i] = rp;
        cursor[i] = rp;
        if (i == N - 1) rowptr[N] = rp + v;
    }
}

__global__ __launch_bounds__(256) void fill_kernel(
    const int* __restrict__ ei, int* __restrict__ cursor, int* __restrict__ col, int E)
{
    int e = blockIdx.x * 256 + threadIdx.x;
    if (e >= E) return;
    int d = ei[E + e];
    int pos = atomicAdd(&cursor[d], 1);
    col[pos] = ei[e];
}

// ================= CSR gather (optional fused BN+ReLU on the gathered input) =================
template<int BN>
__global__ __launch_bounds__(256) void gather_kernel(
    const float* __restrict__ feat, float* __restrict__ agg,
    const int* __restrict__ rowptr, const int* __restrict__ colIdx,
    const float* __restrict__ bnst, int N)
{
    int gid = blockIdx.x * 256 + threadIdx.x;
    int n = gid >> 5;
    if (n >= N) return;
    int l = gid & 31;
    float4 a4, d4;
    if (BN) {
        a4 = *(const float4*)(bnst + 256 + l * 4);
        d4 = *(const float4*)(bnst + 384 + l * 4);
    }
    int beg = rowptr[n], end = rowptr[n + 1];
    float ax = 0.f, ay = 0.f, az = 0.f, aw = 0.f;
    float bx = 0.f, by = 0.f, bz = 0.f, bw = 0.f;
    int e = beg;
    for (; e + 2 <= end; e += 2) {
        int s0 = colIdx[e], s1 = colIdx[e + 1];
        float4 v0 = *(const float4*)(feat + (size_t)s0 * 128 + l * 4);
        float4 v1 = *(const float4*)(feat + (size_t)s1 * 128 + l * 4);
        if (BN) { v0 = bnrelu4(v0, a4, d4); v1 = bnrelu4(v1, a4, d4); }
        ax += v0.x; ay += v0.y; az += v0.z; aw += v0.w;
        bx += v1.x; by += v1.y; bz += v1.z; bw += v1.w;
    }
    if (e < end) {
        int s0 = colIdx[e];
        float4 v0 = *(const float4*)(feat + (size_t)s0 * 128 + l * 4);
        if (BN) v0 = bnrelu4(v0, a4, d4);
        ax += v0.x; ay += v0.y; az += v0.z; aw += v0.w;
    }
    *(float4*)(agg + (size_t)n * 128 + l * 4) =
        make_float4(ax + bx, ay + by, az + bz, aw + bw);
}

// ================= weight prepack: f32 [128][128] -> packed per-matrix [hi|lo] planes =================
// Matrix m at wPk[m*32768..): 16384 hi then 16384 lo.
// idx = kb*4096 + cf*512 + lane*8 + j : element W[kb*32+(lane>>4)*8+j][cf*16+(lane&15)].
__global__ __launch_bounds__(256) void prepack_kernel(
    const float* __restrict__ W0, const float* __restrict__ W1,
    const float* __restrict__ W2, const float* __restrict__ W3,
    const float* __restrict__ W4, const float* __restrict__ W5,
    ushort* __restrict__ wPk)
{
    int m = blockIdx.y;
    const float* W = (m == 0) ? W0 : (m == 1) ? W1 : (m == 2) ? W2
                   : (m == 3) ? W3 : (m == 4) ? W4 : W5;
    int base = m * 32768;
#pragma unroll
    for (int t = 0; t < 8; ++t) {
        int idx = blockIdx.x * 2048 + t * 256 + threadIdx.x;
        int j = idx & 7, l = (idx >> 3) & 63, cf = (idx >> 9) & 7, kb = idx >> 12;
        int k = kb * 32 + (l >> 4) * 8 + j;
        int n = cf * 16 + (l & 15);
        float v = W[k * 128 + n];
        unsigned u = __float_as_uint(v);
        wPk[base + idx] = (ushort)(u >> 16);
        float r = v - __uint_as_float(u & 0xffff0000u);
        wPk[base + 16384 + idx] = (ushort)(__float_as_uint(r) >> 16);
    }
}

// ================= streaming MFMA linear =================
// Barrier-free, LDS-free (gather-style). Block = 4 waves; wave = 16 rows x 32 cols,
// grid-strides over row-tiles. W-hi fragments resident in VGPRs for the wave's life;
// W-lo re-read per tile from L1; A streamed with 1-tile register prefetch.
// BNX: 0 none, 1 = BN+ReLU applied to Xb on load, 2 = applied to Xa on load.
struct TileF { float4 a[8]; float4 b[8]; };

template<int DUAL>
static __device__ __forceinline__ void load_tile(
    const float* __restrict__ Xa, const float* __restrict__ Xb,
    int rt, int s, int q, int nrows, TileF& t)
{
    int row = rt * 16 + s;
    if (row > nrows - 1) row = nrows - 1;
    const float* pa = Xa + (size_t)row * 128 + q * 8;
#pragma unroll
    for (int kb = 0; kb < 4; ++kb) {
        t.a[kb * 2 + 0] = *(const float4*)(pa + kb * 32);
        t.a[kb * 2 + 1] = *(const float4*)(pa + kb * 32 + 4);
    }
    if (DUAL) {
        const float* pb = Xb + (size_t)row * 128 + q * 8;
#pragma unroll
        for (int kb = 0; kb < 4; ++kb) {
            t.b[kb * 2 + 0] = *(const float4*)(pb + kb * 32);
            t.b[kb * 2 + 1] = *(const float4*)(pb + kb * 32 + 4);
        }
    }
}

template<int DUAL, int RELU, int STATS, int BNX>
__global__ __launch_bounds__(256, 2) void slin_kernel(
    const float* __restrict__ Xa, const float* __restrict__ Xb,
    const ushort* __restrict__ WaPk, const ushort* __restrict__ WbPk,
    const float* __restrict__ bias, const float* __restrict__ bnst,
    float* __restrict__ Y, float* __restrict__ stOut, int nrows)
{
    constexpr bool BNA = (BNX == 2);
    constexpr bool BNB = (BNX == 1);
    const int lane = threadIdx.x & 63;
    const int colq = threadIdx.x >> 6;         // 0..3 -> cols colq*32..+31
    const int q = lane >> 4, s = lane & 15;
    const int NT = (nrows + 15) >> 4;
    const int stride = (int)gridDim.x;

    // resident W-hi fragments (cf = colq*2 + c2)
    bf16x8 wha[2][4], whb[2][4];
#pragma unroll
    for (int c2 = 0; c2 < 2; ++c2)
#pragma unroll
        for (int kb = 0; kb < 4; ++kb) {
            size_t off = (size_t)kb * 4096 + (size_t)(colq * 2 + c2) * 512 + lane * 8;
            wha[c2][kb] = *(const bf16x8*)(WaPk + off);
            if (DUAL) whb[c2][kb] = *(const bf16x8*)(WbPk + off);
        }

    const float bv0 = bias[colq * 32 + s];
    const float bv1 = bias[colq * 32 + 16 + s];

    float cs0 = 0.f, cq0 = 0.f, cs1 = 0.f, cq1 = 0.f;

    TileF t;
    const int rt0 = blockIdx.x;
    if (rt0 < NT) load_tile<DUAL>(Xa, Xb, rt0, s, q, nrows, t);

    for (int rt = rt0; rt < NT; rt += stride) {
        // ---- convert current tile to split-bf16 (with optional BN+ReLU) ----
        bf16x8 xah[4], xal[4], xbh[4], xbl[4];
#pragma unroll
        for (int kb = 0; kb < 4; ++kb) {
            float4 f0 = t.a[kb * 2 + 0], f1 = t.a[kb * 2 + 1];
            if (BNA) {
                const float* ab = bnst + 256 + kb * 32 + q * 8;
                f0 = bnrelu4(f0, *(const float4*)ab,       *(const float4*)(ab + 128));
                f1 = bnrelu4(f1, *(const float4*)(ab + 4), *(const float4*)(ab + 132));
            }
            split8(f0, f1, xah[kb], xal[kb]);
            if (DUAL) {
                float4 g0 = t.b[kb * 2 + 0], g1 = t.b[kb * 2 + 1];
                if (BNB) {
                    const float* ab = bnst + 256 + kb * 32 + q * 8;
                    g0 = bnrelu4(g0, *(const float4*)ab,       *(const float4*)(ab + 128));
                    g1 = bnrelu4(g1, *(const float4*)(ab + 4), *(const float4*)(ab + 132));
                }
                split8(g0, g1, xbh[kb], xbl[kb]);
            }
        }
        // ---- prefetch next tile (regs now free; overlaps MFMAs below) ----
        int rtn = rt + stride;
        if (rtn < NT) load_tile<DUAL>(Xa, Xb, rtn, s, q, nrows, t);

        // ---- MFMA ----
        f32x4 acc0 = (f32x4){0.f, 0.f, 0.f, 0.f};
        f32x4 acc1 = (f32x4){0.f, 0.f, 0.f, 0.f};
#pragma unroll
        for (int kb = 0; kb < 4; ++kb) {
            size_t lo = (size_t)16384 + (size_t)kb * 4096 + (size_t)colq * 1024 + lane * 8;
            bf16x8 wla0 = *(const bf16x8*)(WaPk + lo);
            bf16x8 wla1 = *(const bf16x8*)(WaPk + lo + 512);
            acc0 = __builtin_amdgcn_mfma_f32_16x16x32_bf16(xah[kb], wha[0][kb], acc0, 0, 0, 0);
            acc0 = __builtin_amdgcn_mfma_f32_16x16x32_bf16(xal[kb], wha[0][kb], acc0, 0, 0, 0);
            acc0 = __builtin_amdgcn_mfma_f32_16x16x32_bf16(xah[kb], wla0,       acc0, 0, 0, 0);
            acc1 = __builtin_amdgcn_mfma_f32_16x16x32_bf16(xah[kb], wha[1][kb], acc1, 0, 0, 0);
            acc1 = __builtin_amdgcn_mfma_f32_16x16x32_bf16(xal[kb], wha[1][kb], acc1, 0, 0, 0);
            acc1 = __builtin_amdgcn_mfma_f32_16x16x32_bf16(xah[kb], wla1,       acc1, 0, 0, 0);
            if (DUAL) {
                bf16x8 wlb0 = *(const bf16x8*)(WbPk + lo);
                bf16x8 wlb1 = *(const bf16x8*)(WbPk + lo + 512);
                acc0 = __builtin_amdgcn_mfma_f32_16x16x32_bf16(xbh[kb], whb[0][kb], acc0, 0, 0, 0);
                acc0 = __builtin_amdgcn_mfma_f32_16x16x32_bf16(xbl[kb], whb[0][kb], acc0, 0, 0, 0);
                acc0 = __builtin_amdgcn_mfma_f32_16x16x32_bf16(xbh[kb], wlb0,       acc0, 0, 0, 0);
                acc1 = __builtin_amdgcn_mfma_f32_16x16x32_bf16(xbh[kb], whb[1][kb], acc1, 0, 0, 0);
                acc1 = __builtin_amdgcn_mfma_f32_16x16x32_bf16(xbl[kb], whb[1][kb], acc1, 0, 0, 0);
                acc1 = __builtin_amdgcn_mfma_f32_16x16x32_bf16(xbh[kb], wlb1,       acc1, 0, 0, 0);
            }
        }

        // ---- epilogue ----
        int r0 = rt * 16 + q * 4;
#pragma unroll
        for (int i = 0; i < 4; ++i) {
            int r = r0 + i;
            if (r < nrows) {
                float y0 = acc0[i] + bv0;
                float y1 = acc1[i] + bv1;
                if (RELU) { y0 = fmaxf(y0, 0.f); y1 = fmaxf(y1, 0.f); }
                Y[(size_t)r * 128 + colq * 32 + s]      = y0;
                Y[(size_t)r * 128 + colq * 32 + 16 + s] = y1;
                if (STATS) { cs0 += y0; cq0 += y0 * y0; cs1 += y1; cq1 += y1 * y1; }
            }
        }
    }

    if (STATS) {
        cs0 += __shfl_xor(cs0, 16); cs0 += __shfl_xor(cs0, 32);
        cq0 += __shfl_xor(cq0, 16); cq0 += __shfl_xor(cq0, 32);
        cs1 += __shfl_xor(cs1, 16); cs1 += __shfl_xor(cs1, 32);
        cq1 += __shfl_xor(cq1, 16); cq1 += __shfl_xor(cq1, 32);
        if (q == 0) {
            int c0 = colq * 32 + s, c1 = c0 + 16;
            atomicAdd(&stOut[c0], cs0);       atomicAdd(&stOut[128 + c0], cq0);
            atomicAdd(&stOut[c1], cs1);       atomicAdd(&stOut[128 + c1], cq1);
        }
    }
}

// ================= BN finalize: st -> per-column affine (a, d) =================
__global__ void finalize_kernel(float* st, const float* __restrict__ g,
                                const float* __restrict__ be, float inv_n)
{
    int c = threadIdx.x;
    float mu = st[c] * inv_n;
    float var = st[128 + c] * inv_n - mu * mu;
    float rs = rsqrtf(var + EPS);
    float a = g[c] * rs;
    st[256 + c] = a;
    st[384 + c] = be[c] - mu * a;
}

// ================= final projection to DOUT=2 =================
__global__ __launch_bounds__(256) void linout_kernel(
    const float* __restrict__ X, const float* __restrict__ W, const float* __restrict__ b,
    float* __restrict__ out, int nrows)
{
    int r = blockIdx.x * 256 + threadIdx.x;
    if (r >= nrows) return;
    float a0 = 0.f, a1 = 0.f;
    const float* xr = X + (size_t)r * 128;
#pragma unroll 8
    for (int k = 0; k < 128; k += 4) {
        float4 x = *(const float4*)(xr + k);
        a0 += x.x * W[(k + 0) * 2]     + x.y * W[(k + 1) * 2]
            + x.z * W[(k + 2) * 2]     + x.w * W[(k + 3) * 2];
        a1 += x.x * W[(k + 0) * 2 + 1] + x.y * W[(k + 1) * 2 + 1]
            + x.z * W[(k + 2) * 2 + 1] + x.w * W[(k + 3) * 2 + 1];
    }
    float2 o = make_float2(a0 + b[0], a1 + b[1]);
    *(float2*)(out + (size_t)r * 2) = o;
}

extern "C" void kernel_launch(void* const* d_in, const int* in_sizes, int n_in,
                              void* d_out, int out_size, void* d_ws, size_t ws_size,
                              hipStream_t stream) {
    const float* x   = (const float*)d_in[0];
    const int*   ei  = (const int*)d_in[1];
    const float* Wl0 = (const float*)d_in[2];
    const float* bl0 = (const float*)d_in[3];
    const float* Wr0 = (const float*)d_in[4];
    const float* Wl1 = (const float*)d_in[5];
    const float* bl1 = (const float*)d_in[6];
    const float* Wr1 = (const float*)d_in[7];
    const float* g0  = (const float*)d_in[8];
    const float* be0 = (const float*)d_in[9];
    const float* g1  = (const float*)d_in[10];
    const float* be1 = (const float*)d_in[11];
    const float* W1  = (const float*)d_in[12];
    const float* b1  = (const float*)d_in[13];
    const float* W2  = (const float*)d_in[14];
    const float* b2  = (const float*)d_in[15];
    const float* W3  = (const float*)d_in[16];
    const float* b3  = (const float*)d_in[17];
    float* out = (float*)d_out;

    const int N = in_sizes[0] / 128;
    const int E = in_sizes[1] / 2;

    // workspace layout
    float* A   = (float*)d_ws;                   // [N,128]
    float* B   = A + (size_t)N * 128;            // [N,128]
    float* st0 = B + (size_t)N * 128;            // 512 floats
    float* st1 = st0 + 512;                      // 512 floats
    ushort* wPk = (ushort*)(st1 + 512);          // 6 * 32768
    int* deg    = (int*)(wPk + 6 * 32768);       // N
    int* rowptr = deg + N;                       // N+1
    int* cursor = rowptr + N + 1;                // N
    int* col    = cursor + N;                    // E
    int* bsum   = col + E;                       // <=512

    const int SLIN_GRID  = 512;
    const int edgeGrid   = (E + 255) / 256;
    const int nodeGrid   = (N + 255) / 256;
    const int gatherGrid = ((size_t)N * 32 + 255) / 256;
    const float inv_n = 1.0f / (float)N;

    // matrix slots: 0=Wl0 1=Wr0 2=Wl1 3=Wr1 4=W1 5=W2
    prepack_kernel<<<dim3(8, 6), 256, 0, stream>>>(Wl0, Wr0, Wl1, Wr1, W1, W2, wPk);

    // ----- CSR build -----
    hipMemsetAsync(deg, 0, (size_t)N * sizeof(int), stream);
    hist_kernel<<<edgeGrid, 256, 0, stream>>>(ei, deg, E);
    blocksum_kernel<<<nodeGrid, 256, 0, stream>>>(deg, bsum, N);
    scanb_kernel<<<1, 512, 0, stream>>>(bsum, nodeGrid);
    scanfinal_kernel<<<nodeGrid, 256, 0, stream>>>(deg, bsum, rowptr, cursor, N);
    fill_kernel<<<edgeGrid, 256, 0, stream>>>(ei, cursor, col, E);

    // ----- layer 0: A = agg(x); h0_pre = A@Wl0 + x@Wr0 + bl0 (in-place A), stats st0 -----
    gather_kernel<0><<<gatherGrid, 256, 0, stream>>>(x, A, rowptr, col, nullptr, N);
    hipMemsetAsync(st0, 0, 256 * sizeof(float), stream);
    slin_kernel<1, 0, 1, 0><<<SLIN_GRID, 256, 0, stream>>>(
        A, x, wPk, wPk + 32768, bl0, nullptr, A, st0, N);
    finalize_kernel<<<1, 128, 0, stream>>>(st0, g0, be0, inv_n);

    // ----- layer 1: B = agg(bnrelu0(A)); h1_pre = B@Wl1 + bnrelu0(A)@Wr1 + bl1 (in-place B), stats st1 -----
    gather_kernel<1><<<gatherGrid, 256, 0, stream>>>(A, B, rowptr, col, st0, N);
    hipMemsetAsync(st1, 0, 256 * sizeof(float), stream);
    slin_kernel<1, 0, 1, 1><<<SLIN_GRID, 256, 0, stream>>>(
        B, A, wPk + 2 * 32768, wPk + 3 * 32768, bl1, st0, B, st1, N);
    finalize_kernel<<<1, 128, 0, stream>>>(st1, g1, be1, inv_n);

    // ----- MLP head: m1 = relu(bnrelu1(B)@W1 + b1) -> A; m2 = relu(A@W2 + b2) -> B -----
    slin_kernel<0, 1, 0, 2><<<SLIN_GRID, 256, 0, stream>>>(
        B, nullptr, wPk + 4 * 32768, nullptr, b1, st1, A, nullptr, N);
    slin_kernel<0, 1, 0, 0><<<SLIN_GRID, 256, 0, stream>>>(
        A, nullptr, wPk + 5 * 32768, nullptr, b2, nullptr, B, nullptr, N);
    linout_kernel<<<(N + 255) / 256, 256, 0, stream>>>(B, W3, b3, out, N);
}

// Round 12
// 334.929 us; speedup vs baseline: 1.5081x; 1.5081x over previous
//
#include <hip/hip_runtime.h>

#define EPS 1e-5f

typedef __attribute__((ext_vector_type(8))) short bf16x8;
typedef __attribute__((ext_vector_type(4))) float f32x4;

#define GLOBAL_LOAD_LDS16(gp, lp) \
    __builtin_amdgcn_global_load_lds((const __attribute__((address_space(1))) unsigned int*)(gp), \
                                     (__attribute__((address_space(3))) unsigned int*)(lp), 16, 0, 0)

// Split f32 -> bf16 hi (truncated) + bf16 lo (residual, truncated).
static __device__ __forceinline__ void split8(float4 f0, float4 f1, bf16x8& hi, bf16x8& lo) {
    float f[8] = {f0.x, f0.y, f0.z, f0.w, f1.x, f1.y, f1.z, f1.w};
    bf16x8 h, l;
#pragma unroll
    for (int i = 0; i < 8; ++i) {
        unsigned u = __float_as_uint(f[i]);
        h[i] = (short)(u >> 16);
        float r = f[i] - __uint_as_float(u & 0xffff0000u);
        l[i] = (short)(__float_as_uint(r) >> 16);
    }
    hi = h; lo = l;
}

static __device__ __forceinline__ float4 bnrelu4(float4 v, float4 a, float4 d) {
    float4 r;
    r.x = fmaxf(a.x * v.x + d.x, 0.f);
    r.y = fmaxf(a.y * v.y + d.y, 0.f);
    r.z = fmaxf(a.z * v.z + d.z, 0.f);
    r.w = fmaxf(a.w * v.w + d.w, 0.f);
    return r;
}

// ================= CSR build =================
__global__ __launch_bounds__(256) void hist_kernel(
    const int* __restrict__ ei, int* __restrict__ deg, int E)
{
    int e = blockIdx.x * 256 + threadIdx.x;
    if (e >= E) return;
    atomicAdd(&deg[ei[E + e]], 1);
}

__global__ __launch_bounds__(256) void blocksum_kernel(
    const int* __restrict__ deg, int* __restrict__ bsum, int N)
{
    int i = blockIdx.x * 256 + threadIdx.x;
    int v = (i < N) ? deg[i] : 0;
#pragma unroll
    for (int o = 1; o < 64; o <<= 1) v += __shfl_xor(v, o);
    __shared__ int s[4];
    if ((threadIdx.x & 63) == 0) s[threadIdx.x >> 6] = v;
    __syncthreads();
    if (threadIdx.x == 0) bsum[blockIdx.x] = s[0] + s[1] + s[2] + s[3];
}

__global__ __launch_bounds__(512) void scanb_kernel(int* bsum, int NB)
{
    __shared__ int sh[512];
    int t = threadIdx.x;
    int v = (t < NB) ? bsum[t] : 0;
    sh[t] = v;
    __syncthreads();
    for (int o = 1; o < 512; o <<= 1) {
        int add = (t >= o) ? sh[t - o] : 0;
        __syncthreads();
        sh[t] += add;
        __syncthreads();
    }
    if (t < NB) bsum[t] = (t == 0) ? 0 : sh[t - 1];
}

__global__ __launch_bounds__(256) void scanfinal_kernel(
    const int* __restrict__ deg, const int* __restrict__ bsum,
    int* __restrict__ rowptr, int* __restrict__ cursor, int N)
{
    int b = blockIdx.x, t = threadIdx.x;
    int i = b * 256 + t;
    int v = (i < N) ? deg[i] : 0;
    __shared__ int sh[256];
    sh[t] = v;
    __syncthreads();
    for (int o = 1; o < 256; o <<= 1) {
        int add = (t >= o) ? sh[t - o] : 0;
        __syncthreads();
        sh[t] += add;
        __syncthreads();
    }
    int excl = sh[t] - v;
    if (i < N) {
        int rp = bsum[b] + excl;
        rowptr[i] = rp;
        cursor[i] = rp;
        if (i == N - 1) rowptr[N] = rp + v;
    }
}

__global__ __launch_bounds__(256) void fill_kernel(
    const int* __restrict__ ei, int* __restrict__ cursor, int* __restrict__ col, int E)
{
    int e = blockIdx.x * 256 + threadIdx.x;
    if (e >= E) return;
    int d = ei[E + e];
    int pos = atomicAdd(&cursor[d], 1);
    col[pos] = ei[e];
}

// ================= CSR gather (optional fused BN+ReLU on the gathered input) =================
template<int BN>
__global__ __launch_bounds__(256) void gather_kernel(
    const float* __restrict__ feat, float* __restrict__ agg,
    const int* __restrict__ rowptr, const int* __restrict__ colIdx,
    const float* __restrict__ bnst, int N)
{
    int gid = blockIdx.x * 256 + threadIdx.x;
    int n = gid >> 5;
    if (n >= N) return;
    int l = gid & 31;
    float4 a4, d4;
    if (BN) {
        a4 = *(const float4*)(bnst + 256 + l * 4);
        d4 = *(const float4*)(bnst + 384 + l * 4);
    }
    int beg = rowptr[n], end = rowptr[n + 1];
    float ax = 0.f, ay = 0.f, az = 0.f, aw = 0.f;
    float bx = 0.f, by = 0.f, bz = 0.f, bw = 0.f;
    int e = beg;
    for (; e + 2 <= end; e += 2) {
        int s0 = colIdx[e], s1 = colIdx[e + 1];
        float4 v0 = *(const float4*)(feat + (size_t)s0 * 128 + l * 4);
        float4 v1 = *(const float4*)(feat + (size_t)s1 * 128 + l * 4);
        if (BN) { v0 = bnrelu4(v0, a4, d4); v1 = bnrelu4(v1, a4, d4); }
        ax += v0.x; ay += v0.y; az += v0.z; aw += v0.w;
        bx += v1.x; by += v1.y; bz += v1.z; bw += v1.w;
    }
    if (e < end) {
        int s0 = colIdx[e];
        float4 v0 = *(const float4*)(feat + (size_t)s0 * 128 + l * 4);
        if (BN) v0 = bnrelu4(v0, a4, d4);
        ax += v0.x; ay += v0.y; az += v0.z; aw += v0.w;
    }
    *(float4*)(agg + (size_t)n * 128 + l * 4) =
        make_float4(ax + bx, ay + by, az + bz, aw + bw);
}

// ================= weight prepack: f32 [128][128] -> packed per-matrix [hi|lo] planes =================
// Matrix m at wPk[m*32768..): 16384 hi then 16384 lo.
// idx = kb*4096 + cf*512 + lane*8 + j : element W[kb*32+(lane>>4)*8+j][cf*16+(lane&15)].
__global__ __launch_bounds__(256) void prepack_kernel(
    const float* __restrict__ W0, const float* __restrict__ W1,
    const float* __restrict__ W2, const float* __restrict__ W3,
    const float* __restrict__ W4, const float* __restrict__ W5,
    ushort* __restrict__ wPk)
{
    int m = blockIdx.y;
    const float* W = (m == 0) ? W0 : (m == 1) ? W1 : (m == 2) ? W2
                   : (m == 3) ? W3 : (m == 4) ? W4 : W5;
    int base = m * 32768;
#pragma unroll
    for (int t = 0; t < 8; ++t) {
        int idx = blockIdx.x * 2048 + t * 256 + threadIdx.x;
        int j = idx & 7, l = (idx >> 3) & 63, cf = (idx >> 9) & 7, kb = idx >> 12;
        int k = kb * 32 + (l >> 4) * 8 + j;
        int n = cf * 16 + (l & 15);
        float v = W[k * 128 + n];
        unsigned u = __float_as_uint(v);
        wPk[base + idx] = (ushort)(u >> 16);
        float r = v - __uint_as_float(u & 0xffff0000u);
        wPk[base + 16384 + idx] = (ushort)(__float_as_uint(r) >> 16);
    }
}

// ================= persistent B-resident MFMA linear =================
// B (hi+lo planes, both matrices if DUAL) staged into LDS ONCE per block; block then
// grid-strides over 16-row tiles. Per tile: coalesced full-row loads -> regs (BN fused)
// -> XOR-swizzled ds_write; compute = ds_read + split8 + MFMA only (no global loads).
// Wave w (0..7) owns output cols w*16..+15. Stats accumulate in registers across the
// persistent run; one atomic set per thread at the end.
// BN semantics: DUAL -> applied to Xb; single -> applied to Xa.
template<int DUAL, int RELU, int STATS, int BN>
__global__ __launch_bounds__(512, 2) void plin_kernel(
    const float* __restrict__ Xa, const float* __restrict__ Xb,
    const ushort* __restrict__ wPair, const float* __restrict__ bias,
    const float* __restrict__ bnst, float* __restrict__ Y,
    float* __restrict__ stOut, int nrows)
{
    extern __shared__ ushort lds[];
    ushort* ldsB = lds;                                       // DUAL?131072B:65536B
    float*  ldsA = (float*)(lds + (DUAL ? 65536 : 32768));    // 16KB / 8KB
    const int tid  = threadIdx.x;
    const int lane = tid & 63;
    const int w    = tid >> 6;                                // wave = output col group
    const int q = lane >> 4, s = lane & 15;

    // ---- stage all B planes once (linear 1KB chunks) ----
    {
        const int npass = DUAL ? 16 : 8;
#pragma unroll
        for (int p = 0; p < npass; ++p) {
            int cid = p * 8 + w;
            GLOBAL_LOAD_LDS16(wPair + (size_t)cid * 512 + lane * 8, ldsB + (size_t)cid * 512);
        }
    }

    // per-thread staging coords: thread covers 16B unit (srow, sunit) of the tile
    const int srow  = tid >> 5;       // 0..15
    const int sunit = tid & 31;       // 0..31 (16B units across the 512B row)
    const int sux   = sunit ^ (srow & 7);
    float4 bna, bnd;
    if (BN) {
        bna = *(const float4*)(bnst + 256 + sunit * 4);
        bnd = *(const float4*)(bnst + 384 + sunit * 4);
    }

    const int colc = w * 16 + s;
    const float bv = bias[colc];
    float cs = 0.f, cq = 0.f;

    const int NT = (nrows + 15) >> 4;
    const int stride = (int)gridDim.x;
    const int t0 = blockIdx.x;

    // prologue: stage tile t0
    if (t0 < NT) {
        int row = t0 * 16 + srow; if (row > nrows - 1) row = nrows - 1;
        float4 va = *(const float4*)(Xa + (size_t)row * 128 + sunit * 4);
        float4 vb;
        if (DUAL) vb = *(const float4*)(Xb + (size_t)row * 128 + sunit * 4);
        if (BN) { if (DUAL) vb = bnrelu4(vb, bna, bnd); else va = bnrelu4(va, bna, bnd); }
        *(float4*)(ldsA + srow * 128 + sux * 4) = va;
        if (DUAL) *(float4*)(ldsA + 2048 + srow * 128 + sux * 4) = vb;
    }

    for (int t = t0; t < NT; t += stride) {
        int tn = t + stride;
        float4 na, nb;
        if (tn < NT) {   // issue next tile's loads early (latency hides under compute)
            int row = tn * 16 + srow; if (row > nrows - 1) row = nrows - 1;
            na = *(const float4*)(Xa + (size_t)row * 128 + sunit * 4);
            if (DUAL) nb = *(const float4*)(Xb + (size_t)row * 128 + sunit * 4);
        }
        __syncthreads();   // staged A (and B on first iter) visible

        f32x4 acc = (f32x4){0.f, 0.f, 0.f, 0.f};
#pragma unroll
        for (int m = 0; m <= DUAL; ++m) {
            const float*  ar = ldsA + m * 2048 + s * 128;
            const ushort* br = ldsB + m * 32768 + w * 512 + lane * 8;
#pragma unroll
            for (int kb = 0; kb < 4; ++kb) {
                int u0 = kb * 8 + q * 2;
                float4 f0 = *(const float4*)(ar + ((u0 + 0) ^ (s & 7)) * 4);
                float4 f1 = *(const float4*)(ar + ((u0 + 1) ^ (s & 7)) * 4);
                bf16x8 ah, al;
                split8(f0, f1, ah, al);
                bf16x8 bh = *(const bf16x8*)(br + kb * 4096);
                bf16x8 bl = *(const bf16x8*)(br + 16384 + kb * 4096);
                acc = __builtin_amdgcn_mfma_f32_16x16x32_bf16(ah, bh, acc, 0, 0, 0);
                acc = __builtin_amdgcn_mfma_f32_16x16x32_bf16(al, bh, acc, 0, 0, 0);
                acc = __builtin_amdgcn_mfma_f32_16x16x32_bf16(ah, bl, acc, 0, 0, 0);
            }
        }

        // epilogue: 16 lanes write 64B contiguous; block covers all 128 cols
        int r0 = t * 16 + q * 4;
#pragma unroll
        for (int i = 0; i < 4; ++i) {
            int r = r0 + i;
            if (r < nrows) {
                float y = acc[i] + bv;
                if (RELU) y = fmaxf(y, 0.f);
                Y[(size_t)r * 128 + colc] = y;
                if (STATS) { cs += y; cq += y * y; }
            }
        }
        __syncthreads();   // all ldsA reads done
        if (tn < NT) {
            if (BN) { if (DUAL) nb = bnrelu4(nb, bna, bnd); else na = bnrelu4(na, bna, bnd); }
            *(float4*)(ldsA + srow * 128 + sux * 4) = na;
            if (DUAL) *(float4*)(ldsA + 2048 + srow * 128 + sux * 4) = nb;
        }
    }

    if (STATS) {
        cs += __shfl_xor(cs, 16); cs += __shfl_xor(cs, 32);
        cq += __shfl_xor(cq, 16); cq += __shfl_xor(cq, 32);
        if (q == 0) {
            atomicAdd(&stOut[colc], cs);
            atomicAdd(&stOut[128 + colc], cq);
        }
    }
}

// ================= BN finalize: st -> per-column affine (a, d) =================
__global__ void finalize_kernel(float* st, const float* __restrict__ g,
                                const float* __restrict__ be, float inv_n)
{
    int c = threadIdx.x;
    float mu = st[c] * inv_n;
    float var = st[128 + c] * inv_n - mu * mu;
    float rs = rsqrtf(var + EPS);
    float a = g[c] * rs;
    st[256 + c] = a;
    st[384 + c] = be[c] - mu * a;
}

// ================= final projection to DOUT=2 =================
__global__ __launch_bounds__(256) void linout_kernel(
    const float* __restrict__ X, const float* __restrict__ W, const float* __restrict__ b,
    float* __restrict__ out, int nrows)
{
    int r = blockIdx.x * 256 + threadIdx.x;
    if (r >= nrows) return;
    float a0 = 0.f, a1 = 0.f;
    const float* xr = X + (size_t)r * 128;
#pragma unroll 8
    for (int k = 0; k < 128; k += 4) {
        float4 x = *(const float4*)(xr + k);
        a0 += x.x * W[(k + 0) * 2]     + x.y * W[(k + 1) * 2]
            + x.z * W[(k + 2) * 2]     + x.w * W[(k + 3) * 2];
        a1 += x.x * W[(k + 0) * 2 + 1] + x.y * W[(k + 1) * 2 + 1]
            + x.z * W[(k + 2) * 2 + 1] + x.w * W[(k + 3) * 2 + 1];
    }
    float2 o = make_float2(a0 + b[0], a1 + b[1]);
    *(float2*)(out + (size_t)r * 2) = o;
}

extern "C" void kernel_launch(void* const* d_in, const int* in_sizes, int n_in,
                              void* d_out, int out_size, void* d_ws, size_t ws_size,
                              hipStream_t stream) {
    const float* x   = (const float*)d_in[0];
    const int*   ei  = (const int*)d_in[1];
    const float* Wl0 = (const float*)d_in[2];
    const float* bl0 = (const float*)d_in[3];
    const float* Wr0 = (const float*)d_in[4];
    const float* Wl1 = (const float*)d_in[5];
    const float* bl1 = (const float*)d_in[6];
    const float* Wr1 = (const float*)d_in[7];
    const float* g0  = (const float*)d_in[8];
    const float* be0 = (const float*)d_in[9];
    const float* g1  = (const float*)d_in[10];
    const float* be1 = (const float*)d_in[11];
    const float* W1  = (const float*)d_in[12];
    const float* b1  = (const float*)d_in[13];
    const float* W2  = (const float*)d_in[14];
    const float* b2  = (const float*)d_in[15];
    const float* W3  = (const float*)d_in[16];
    const float* b3  = (const float*)d_in[17];
    float* out = (float*)d_out;

    const int N = in_sizes[0] / 128;
    const int E = in_sizes[1] / 2;

    // workspace layout
    float* A   = (float*)d_ws;                   // [N,128]
    float* B   = A + (size_t)N * 128;            // [N,128]
    float* st0 = B + (size_t)N * 128;            // 512 floats
    float* st1 = st0 + 512;                      // 512 floats
    ushort* wPk = (ushort*)(st1 + 512);          // 6 * 32768
    int* deg    = (int*)(wPk + 6 * 32768);       // N
    int* rowptr = deg + N;                       // N+1
    int* cursor = rowptr + N + 1;                // N
    int* col    = cursor + N;                    // E
    int* bsum   = col + E;                       // <=512

    const int edgeGrid   = (E + 255) / 256;
    const int nodeGrid   = (N + 255) / 256;
    const int gatherGrid = ((size_t)N * 32 + 255) / 256;
    const float inv_n = 1.0f / (float)N;
    const size_t shDual = 147456;   // 128KB B + 16KB A
    const size_t shSing = 73728;    // 64KB B + 8KB A

    // matrix slots: 0=Wl0 1=Wr0 2=Wl1 3=Wr1 4=W1 5=W2 (dual pairs adjacent)
    prepack_kernel<<<dim3(8, 6), 256, 0, stream>>>(Wl0, Wr0, Wl1, Wr1, W1, W2, wPk);

    // ----- CSR build -----
    hipMemsetAsync(deg, 0, (size_t)N * sizeof(int), stream);
    hist_kernel<<<edgeGrid, 256, 0, stream>>>(ei, deg, E);
    blocksum_kernel<<<nodeGrid, 256, 0, stream>>>(deg, bsum, N);
    scanb_kernel<<<1, 512, 0, stream>>>(bsum, nodeGrid);
    scanfinal_kernel<<<nodeGrid, 256, 0, stream>>>(deg, bsum, rowptr, cursor, N);
    fill_kernel<<<edgeGrid, 256, 0, stream>>>(ei, cursor, col, E);

    // ----- layer 0: A = agg(x); h0_pre = A@Wl0 + x@Wr0 + bl0 (in-place A), stats st0 -----
    gather_kernel<0><<<gatherGrid, 256, 0, stream>>>(x, A, rowptr, col, nullptr, N);
    hipMemsetAsync(st0, 0, 256 * sizeof(float), stream);
    plin_kernel<1, 0, 1, 0><<<256, 512, shDual, stream>>>(
        A, x, wPk, bl0, nullptr, A, st0, N);
    finalize_kernel<<<1, 128, 0, stream>>>(st0, g0, be0, inv_n);

    // ----- layer 1: B = agg(bnrelu0(A)); h1_pre = B@Wl1 + bnrelu0(A)@Wr1 + bl1, stats st1 -----
    gather_kernel<1><<<gatherGrid, 256, 0, stream>>>(A, B, rowptr, col, st0, N);
    hipMemsetAsync(st1, 0, 256 * sizeof(float), stream);
    plin_kernel<1, 0, 1, 1><<<256, 512, shDual, stream>>>(
        B, A, wPk + 2 * 32768, bl1, st0, B, st1, N);
    finalize_kernel<<<1, 128, 0, stream>>>(st1, g1, be1, inv_n);

    // ----- MLP head: A = relu(bnrelu1(B)@W1 + b1); B = relu(A@W2 + b2) -----
    plin_kernel<0, 1, 0, 1><<<512, 512, shSing, stream>>>(
        B, nullptr, wPk + 4 * 32768, b1, st1, A, nullptr, N);
    plin_kernel<0, 1, 0, 0><<<512, 512, shSing, stream>>>(
        A, nullptr, wPk + 5 * 32768, b2, nullptr, B, nullptr, N);
    linout_kernel<<<(N + 255) / 256, 256, 0, stream>>>(B, W3, b3, out, N);
}

// Round 13
// 299.343 us; speedup vs baseline: 1.6874x; 1.1189x over previous
//
#include <hip/hip_runtime.h>

#define EPS 1e-5f

typedef __attribute__((ext_vector_type(8))) short bf16x8;
typedef __attribute__((ext_vector_type(4))) float f32x4;

// Split f32x4 -> 4 bf16 hi (truncated) + 4 bf16 lo (residual, truncated).
static __device__ __forceinline__ void split4(float4 f, ushort4& hi, ushort4& lo) {
    float v[4] = {f.x, f.y, f.z, f.w};
    ushort h[4], l[4];
#pragma unroll
    for (int i = 0; i < 4; ++i) {
        unsigned u = __float_as_uint(v[i]);
        h[i] = (ushort)(u >> 16);
        float r = v[i] - __uint_as_float(u & 0xffff0000u);
        l[i] = (ushort)(__float_as_uint(r) >> 16);
    }
    hi = make_ushort4(h[0], h[1], h[2], h[3]);
    lo = make_ushort4(l[0], l[1], l[2], l[3]);
}

static __device__ __forceinline__ float4 bnrelu4(float4 v, float4 a, float4 d) {
    float4 r;
    r.x = fmaxf(a.x * v.x + d.x, 0.f);
    r.y = fmaxf(a.y * v.y + d.y, 0.f);
    r.z = fmaxf(a.z * v.z + d.z, 0.f);
    r.w = fmaxf(a.w * v.w + d.w, 0.f);
    return r;
}

// ================= CSR build =================
__global__ __launch_bounds__(256) void hist_kernel(
    const int* __restrict__ ei, int* __restrict__ deg, int E)
{
    int e = blockIdx.x * 256 + threadIdx.x;
    if (e >= E) return;
    atomicAdd(&deg[ei[E + e]], 1);
}

__global__ __launch_bounds__(256) void blocksum_kernel(
    const int* __restrict__ deg, int* __restrict__ bsum, int N)
{
    int i = blockIdx.x * 256 + threadIdx.x;
    int v = (i < N) ? deg[i] : 0;
#pragma unroll
    for (int o = 1; o < 64; o <<= 1) v += __shfl_xor(v, o);
    __shared__ int s[4];
    if ((threadIdx.x & 63) == 0) s[threadIdx.x >> 6] = v;
    __syncthreads();
    if (threadIdx.x == 0) bsum[blockIdx.x] = s[0] + s[1] + s[2] + s[3];
}

__global__ __launch_bounds__(512) void scanb_kernel(int* bsum, int NB)
{
    __shared__ int sh[512];
    int t = threadIdx.x;
    int v = (t < NB) ? bsum[t] : 0;
    sh[t] = v;
    __syncthreads();
    for (int o = 1; o < 512; o <<= 1) {
        int add = (t >= o) ? sh[t - o] : 0;
        __syncthreads();
        sh[t] += add;
        __syncthreads();
    }
    if (t < NB) bsum[t] = (t == 0) ? 0 : sh[t - 1];
}

__global__ __launch_bounds__(256) void scanfinal_kernel(
    const int* __restrict__ deg, const int* __restrict__ bsum,
    int* __restrict__ rowptr, int* __restrict__ cursor, int N)
{
    int b = blockIdx.x, t = threadIdx.x;
    int i = b * 256 + t;
    int v = (i < N) ? deg[i] : 0;
    __shared__ int sh[256];
    sh[t] = v;
    __syncthreads();
    for (int o = 1; o < 256; o <<= 1) {
        int add = (t >= o) ? sh[t - o] : 0;
        __syncthreads();
        sh[t] += add;
        __syncthreads();
    }
    int excl = sh[t] - v;
    if (i < N) {
        int rp = bsum[b] + excl;
        rowptr[i] = rp;
        cursor[i] = rp;
        if (i == N - 1) rowptr[N] = rp + v;
    }
}

__global__ __launch_bounds__(256) void fill_kernel(
    const int* __restrict__ ei, int* __restrict__ cursor, int* __restrict__ col, int E)
{
    int e = blockIdx.x * 256 + threadIdx.x;
    if (e >= E) return;
    int d = ei[E + e];
    int pos = atomicAdd(&cursor[d], 1);
    col[pos] = ei[e];
}

// ================= CSR gather (optional fused BN+ReLU on the gathered input) =================
template<int BN>
__global__ __launch_bounds__(256) void gather_kernel(
    const float* __restrict__ feat, float* __restrict__ agg,
    const int* __restrict__ rowptr, const int* __restrict__ colIdx,
    const float* __restrict__ bnst, int N)
{
    int gid = blockIdx.x * 256 + threadIdx.x;
    int n = gid >> 5;
    if (n >= N) return;
    int l = gid & 31;
    float4 a4, d4;
    if (BN) {
        a4 = *(const float4*)(bnst + 256 + l * 4);
        d4 = *(const float4*)(bnst + 384 + l * 4);
    }
    int beg = rowptr[n], end = rowptr[n + 1];
    float ax = 0.f, ay = 0.f, az = 0.f, aw = 0.f;
    float bx = 0.f, by = 0.f, bz = 0.f, bw = 0.f;
    int e = beg;
    for (; e + 2 <= end; e += 2) {
        int s0 = colIdx[e], s1 = colIdx[e + 1];
        float4 v0 = *(const float4*)(feat + (size_t)s0 * 128 + l * 4);
        float4 v1 = *(const float4*)(feat + (size_t)s1 * 128 + l * 4);
        if (BN) { v0 = bnrelu4(v0, a4, d4); v1 = bnrelu4(v1, a4, d4); }
        ax += v0.x; ay += v0.y; az += v0.z; aw += v0.w;
        bx += v1.x; by += v1.y; bz += v1.z; bw += v1.w;
    }
    if (e < end) {
        int s0 = colIdx[e];
        float4 v0 = *(const float4*)(feat + (size_t)s0 * 128 + l * 4);
        if (BN) v0 = bnrelu4(v0, a4, d4);
        ax += v0.x; ay += v0.y; az += v0.z; aw += v0.w;
    }
    *(float4*)(agg + (size_t)n * 128 + l * 4) =
        make_float4(ax + bx, ay + by, az + bz, aw + bw);
}

// ================= weight prepack: f32 [128][128] -> packed per-matrix [hi|lo] planes =================
// Matrix m at wPk[m*32768..): 16384 hi then 16384 lo.
// idx = kb*4096 + cf*512 + lane*8 + j : element W[kb*32+(lane>>4)*8+j][cf*16+(lane&15)].
__global__ __launch_bounds__(256) void prepack_kernel(
    const float* __restrict__ W0, const float* __restrict__ W1,
    const float* __restrict__ W2, const float* __restrict__ W3,
    const float* __restrict__ W4, const float* __restrict__ W5,
    ushort* __restrict__ wPk)
{
    int m = blockIdx.y;
    const float* W = (m == 0) ? W0 : (m == 1) ? W1 : (m == 2) ? W2
                   : (m == 3) ? W3 : (m == 4) ? W4 : W5;
    int base = m * 32768;
#pragma unroll
    for (int t = 0; t < 8; ++t) {
        int idx = blockIdx.x * 2048 + t * 256 + threadIdx.x;
        int j = idx & 7, l = (idx >> 3) & 63, cf = (idx >> 9) & 7, kb = idx >> 12;
        int k = kb * 32 + (l >> 4) * 8 + j;
        int n = cf * 16 + (l & 15);
        float v = W[k * 128 + n];
        unsigned u = __float_as_uint(v);
        wPk[base + idx] = (ushort)(u >> 16);
        float r = v - __uint_as_float(u & 0xffff0000u);
        wPk[base + 16384 + idx] = (ushort)(__float_as_uint(r) >> 16);
    }
}

// ================= persistent MFMA linear: B in VGPRs, A split-once in LDS =================
// Each lane holds its wave's B fragments (hi+lo, both matrices if DUAL) in registers for
// the kernel's life (loaded once from global). Block grid-strides over 16-row tiles:
// staging threads load f32 rows coalesced, apply fused BN, split8 ONCE, write padded
// bf16 hi/lo planes to LDS (row stride 136 bf16 = 17 granules -> rotating banks).
// Compute = ds_read_b128 (bf16 frags) + MFMA only. Stats accumulate in registers.
// BN semantics: DUAL -> applied to Xb; single -> applied to Xa.
template<int DUAL, int RELU, int STATS, int BN>
__global__ __launch_bounds__(512, 2) void plin_kernel(
    const float* __restrict__ Xa, const float* __restrict__ Xb,
    const ushort* __restrict__ wPair, const float* __restrict__ bias,
    const float* __restrict__ bnst, float* __restrict__ Y,
    float* __restrict__ stOut, int nrows)
{
    // planes: [m][hi/lo][16 rows][136 bf16]  (plane stride 2176 ushorts = 4352B)
    __shared__ ushort ldsA[(DUAL ? 2 : 1) * 2 * 2176];
    const int tid  = threadIdx.x;
    const int lane = tid & 63;
    const int w    = tid >> 6;            // wave = output col group (cols w*16..+15)
    const int q = lane >> 4, s = lane & 15;

    // ---- B fragments -> registers (once) ----
    constexpr int NM = DUAL + 1;
    bf16x8 wf[NM][4][2];
#pragma unroll
    for (int m = 0; m < NM; ++m)
#pragma unroll
        for (int kb = 0; kb < 4; ++kb) {
            size_t o = (size_t)m * 32768 + (size_t)kb * 4096 + w * 512 + lane * 8;
            wf[m][kb][0] = *(const bf16x8*)(wPair + o);
            wf[m][kb][1] = *(const bf16x8*)(wPair + o + 16384);
        }

    // staging coords: thread covers float4 unit (srow, sunit)
    const int srow  = tid >> 5;           // 0..15
    const int sunit = tid & 31;           // 0..31
    float4 bna, bnd;
    if (BN) {
        bna = *(const float4*)(bnst + 256 + sunit * 4);
        bnd = *(const float4*)(bnst + 384 + sunit * 4);
    }

    const int colc = w * 16 + s;
    const float bv = bias[colc];
    float cs = 0.f, cq = 0.f;

    const int NT = (nrows + 15) >> 4;
    const int stride = (int)gridDim.x;
    const int t0 = blockIdx.x;
    const int woff = srow * 136 + sunit * 4;   // ushort offset within a plane

    // prologue: stage tile t0
    if (t0 < NT) {
        int row = t0 * 16 + srow; if (row > nrows - 1) row = nrows - 1;
        float4 va = *(const float4*)(Xa + (size_t)row * 128 + sunit * 4);
        float4 vb;
        if (DUAL) vb = *(const float4*)(Xb + (size_t)row * 128 + sunit * 4);
        if (BN) { if (DUAL) vb = bnrelu4(vb, bna, bnd); else va = bnrelu4(va, bna, bnd); }
        ushort4 h, l;
        split4(va, h, l);
        *(ushort4*)(ldsA + woff)        = h;
        *(ushort4*)(ldsA + 2176 + woff) = l;
        if (DUAL) {
            split4(vb, h, l);
            *(ushort4*)(ldsA + 4352 + woff) = h;
            *(ushort4*)(ldsA + 6528 + woff) = l;
        }
    }

    for (int t = t0; t < NT; t += stride) {
        int tn = t + stride;
        float4 na, nb;
        if (tn < NT) {   // issue next tile's loads early (latency hides under compute)
            int row = tn * 16 + srow; if (row > nrows - 1) row = nrows - 1;
            na = *(const float4*)(Xa + (size_t)row * 128 + sunit * 4);
            if (DUAL) nb = *(const float4*)(Xb + (size_t)row * 128 + sunit * 4);
        }
        __syncthreads();   // staged planes visible

        f32x4 acc = (f32x4){0.f, 0.f, 0.f, 0.f};
#pragma unroll
        for (int m = 0; m < NM; ++m) {
            const ushort* pm = ldsA + m * 4352 + s * 136;
#pragma unroll
            for (int kb = 0; kb < 4; ++kb) {
                bf16x8 ah = *(const bf16x8*)(pm + (kb * 4 + q) * 8);
                bf16x8 al = *(const bf16x8*)(pm + 2176 + (kb * 4 + q) * 8);
                acc = __builtin_amdgcn_mfma_f32_16x16x32_bf16(ah, wf[m][kb][0], acc, 0, 0, 0);
                acc = __builtin_amdgcn_mfma_f32_16x16x32_bf16(al, wf[m][kb][0], acc, 0, 0, 0);
                acc = __builtin_amdgcn_mfma_f32_16x16x32_bf16(ah, wf[m][kb][1], acc, 0, 0, 0);
            }
        }

        // epilogue: 16 lanes write 64B contiguous; 8 waves cover all 128 cols
        int r0 = t * 16 + q * 4;
#pragma unroll
        for (int i = 0; i < 4; ++i) {
            int r = r0 + i;
            if (r < nrows) {
                float y = acc[i] + bv;
                if (RELU) y = fmaxf(y, 0.f);
                Y[(size_t)r * 128 + colc] = y;
                if (STATS) { cs += y; cq += y * y; }
            }
        }
        __syncthreads();   // all plane reads done
        if (tn < NT) {
            if (BN) { if (DUAL) nb = bnrelu4(nb, bna, bnd); else na = bnrelu4(na, bna, bnd); }
            ushort4 h, l;
            split4(na, h, l);
            *(ushort4*)(ldsA + woff)        = h;
            *(ushort4*)(ldsA + 2176 + woff) = l;
            if (DUAL) {
                split4(nb, h, l);
                *(ushort4*)(ldsA + 4352 + woff) = h;
                *(ushort4*)(ldsA + 6528 + woff) = l;
            }
        }
    }

    if (STATS) {
        cs += __shfl_xor(cs, 16); cs += __shfl_xor(cs, 32);
        cq += __shfl_xor(cq, 16); cq += __shfl_xor(cq, 32);
        if (q == 0) {
            atomicAdd(&stOut[colc], cs);
            atomicAdd(&stOut[128 + colc], cq);
        }
    }
}

// ================= BN finalize: st -> per-column affine (a, d) =================
__global__ void finalize_kernel(float* st, const float* __restrict__ g,
                                const float* __restrict__ be, float inv_n)
{
    int c = threadIdx.x;
    float mu = st[c] * inv_n;
    float var = st[128 + c] * inv_n - mu * mu;
    float rs = rsqrtf(var + EPS);
    float a = g[c] * rs;
    st[256 + c] = a;
    st[384 + c] = be[c] - mu * a;
}

// ================= final projection to DOUT=2 =================
__global__ __launch_bounds__(256) void linout_kernel(
    const float* __restrict__ X, const float* __restrict__ W, const float* __restrict__ b,
    float* __restrict__ out, int nrows)
{
    int r = blockIdx.x * 256 + threadIdx.x;
    if (r >= nrows) return;
    float a0 = 0.f, a1 = 0.f;
    const float* xr = X + (size_t)r * 128;
#pragma unroll 8
    for (int k = 0; k < 128; k += 4) {
        float4 x = *(const float4*)(xr + k);
        a0 += x.x * W[(k + 0) * 2]     + x.y * W[(k + 1) * 2]
            + x.z * W[(k + 2) * 2]     + x.w * W[(k + 3) * 2];
        a1 += x.x * W[(k + 0) * 2 + 1] + x.y * W[(k + 1) * 2 + 1]
            + x.z * W[(k + 2) * 2 + 1] + x.w * W[(k + 3) * 2 + 1];
    }
    float2 o = make_float2(a0 + b[0], a1 + b[1]);
    *(float2*)(out + (size_t)r * 2) = o;
}

extern "C" void kernel_launch(void* const* d_in, const int* in_sizes, int n_in,
                              void* d_out, int out_size, void* d_ws, size_t ws_size,
                              hipStream_t stream) {
    const float* x   = (const float*)d_in[0];
    const int*   ei  = (const int*)d_in[1];
    const float* Wl0 = (const float*)d_in[2];
    const float* bl0 = (const float*)d_in[3];
    const float* Wr0 = (const float*)d_in[4];
    const float* Wl1 = (const float*)d_in[5];
    const float* bl1 = (const float*)d_in[6];
    const float* Wr1 = (const float*)d_in[7];
    const float* g0  = (const float*)d_in[8];
    const float* be0 = (const float*)d_in[9];
    const float* g1  = (const float*)d_in[10];
    const float* be1 = (const float*)d_in[11];
    const float* W1  = (const float*)d_in[12];
    const float* b1  = (const float*)d_in[13];
    const float* W2  = (const float*)d_in[14];
    const float* b2  = (const float*)d_in[15];
    const float* W3  = (const float*)d_in[16];
    const float* b3  = (const float*)d_in[17];
    float* out = (float*)d_out;

    const int N = in_sizes[0] / 128;
    const int E = in_sizes[1] / 2;

    // workspace layout
    float* A   = (float*)d_ws;                   // [N,128]
    float* B   = A + (size_t)N * 128;            // [N,128]
    float* st0 = B + (size_t)N * 128;            // 512 floats
    float* st1 = st0 + 512;                      // 512 floats
    ushort* wPk = (ushort*)(st1 + 512);          // 6 * 32768
    int* deg    = (int*)(wPk + 6 * 32768);       // N
    int* rowptr = deg + N;                       // N+1
    int* cursor = rowptr + N + 1;                // N
    int* col    = cursor + N;                    // E
    int* bsum   = col + E;                       // <=512

    const int edgeGrid   = (E + 255) / 256;
    const int nodeGrid   = (N + 255) / 256;
    const int gatherGrid = ((size_t)N * 32 + 255) / 256;
    const float inv_n = 1.0f / (float)N;

    // matrix slots: 0=Wl0 1=Wr0 2=Wl1 3=Wr1 4=W1 5=W2 (dual pairs adjacent)
    prepack_kernel<<<dim3(8, 6), 256, 0, stream>>>(Wl0, Wr0, Wl1, Wr1, W1, W2, wPk);

    // ----- CSR build -----
    hipMemsetAsync(deg, 0, (size_t)N * sizeof(int), stream);
    hist_kernel<<<edgeGrid, 256, 0, stream>>>(ei, deg, E);
    blocksum_kernel<<<nodeGrid, 256, 0, stream>>>(deg, bsum, N);
    scanb_kernel<<<1, 512, 0, stream>>>(bsum, nodeGrid);
    scanfinal_kernel<<<nodeGrid, 256, 0, stream>>>(deg, bsum, rowptr, cursor, N);
    fill_kernel<<<edgeGrid, 256, 0, stream>>>(ei, cursor, col, E);

    // ----- layer 0: A = agg(x); h0_pre = A@Wl0 + x@Wr0 + bl0 (in-place A), stats st0 -----
    gather_kernel<0><<<gatherGrid, 256, 0, stream>>>(x, A, rowptr, col, nullptr, N);
    hipMemsetAsync(st0, 0, 256 * sizeof(float), stream);
    plin_kernel<1, 0, 1, 0><<<512, 512, 0, stream>>>(
        A, x, wPk, bl0, nullptr, A, st0, N);
    finalize_kernel<<<1, 128, 0, stream>>>(st0, g0, be0, inv_n);

    // ----- layer 1: B = agg(bnrelu0(A)); h1_pre = B@Wl1 + bnrelu0(A)@Wr1 + bl1, stats st1 -----
    gather_kernel<1><<<gatherGrid, 256, 0, stream>>>(A, B, rowptr, col, st0, N);
    hipMemsetAsync(st1, 0, 256 * sizeof(float), stream);
    plin_kernel<1, 0, 1, 1><<<512, 512, 0, stream>>>(
        B, A, wPk + 2 * 32768, bl1, st0, B, st1, N);
    finalize_kernel<<<1, 128, 0, stream>>>(st1, g1, be1, inv_n);

    // ----- MLP head: A = relu(bnrelu1(B)@W1 + b1); B = relu(A@W2 + b2) -----
    plin_kernel<0, 1, 0, 1><<<512, 512, 0, stream>>>(
        B, nullptr, wPk + 4 * 32768, b1, st1, A, nullptr, N);
    plin_kernel<0, 1, 0, 0><<<512, 512, 0, stream>>>(
        A, nullptr, wPk + 5 * 32768, b2, nullptr, B, nullptr, N);
    linout_kernel<<<(N + 255) / 256, 256, 0, stream>>>(B, W3, b3, out, N);
}

// Round 14
// 276.279 us; speedup vs baseline: 1.8282x; 1.0835x over previous
//
#include <hip/hip_runtime.h>

#define EPS 1e-5f

typedef __attribute__((ext_vector_type(8))) short bf16x8;
typedef __attribute__((ext_vector_type(4))) float f32x4;

// Split f32x4 -> 4 bf16 hi (truncated) + 4 bf16 lo (residual, truncated).
static __device__ __forceinline__ void split4(float4 f, ushort4& hi, ushort4& lo) {
    float v[4] = {f.x, f.y, f.z, f.w};
    ushort h[4], l[4];
#pragma unroll
    for (int i = 0; i < 4; ++i) {
        unsigned u = __float_as_uint(v[i]);
        h[i] = (ushort)(u >> 16);
        float r = v[i] - __uint_as_float(u & 0xffff0000u);
        l[i] = (ushort)(__float_as_uint(r) >> 16);
    }
    hi = make_ushort4(h[0], h[1], h[2], h[3]);
    lo = make_ushort4(l[0], l[1], l[2], l[3]);
}

static __device__ __forceinline__ float4 bnrelu4(float4 v, float4 a, float4 d) {
    float4 r;
    r.x = fmaxf(a.x * v.x + d.x, 0.f);
    r.y = fmaxf(a.y * v.y + d.y, 0.f);
    r.z = fmaxf(a.z * v.z + d.z, 0.f);
    r.w = fmaxf(a.w * v.w + d.w, 0.f);
    return r;
}

// ================= CSR build =================
__global__ __launch_bounds__(256) void hist_kernel(
    const int* __restrict__ ei, int* __restrict__ deg, int E)
{
    int e = blockIdx.x * 256 + threadIdx.x;
    if (e >= E) return;
    atomicAdd(&deg[ei[E + e]], 1);
}

__global__ __launch_bounds__(256) void blocksum_kernel(
    const int* __restrict__ deg, int* __restrict__ bsum, int N)
{
    int i = blockIdx.x * 256 + threadIdx.x;
    int v = (i < N) ? deg[i] : 0;
#pragma unroll
    for (int o = 1; o < 64; o <<= 1) v += __shfl_xor(v, o);
    __shared__ int s[4];
    if ((threadIdx.x & 63) == 0) s[threadIdx.x >> 6] = v;
    __syncthreads();
    if (threadIdx.x == 0) bsum[blockIdx.x] = s[0] + s[1] + s[2] + s[3];
}

__global__ __launch_bounds__(512) void scanb_kernel(int* bsum, int NB)
{
    __shared__ int sh[512];
    int t = threadIdx.x;
    int v = (t < NB) ? bsum[t] : 0;
    sh[t] = v;
    __syncthreads();
    for (int o = 1; o < 512; o <<= 1) {
        int add = (t >= o) ? sh[t - o] : 0;
        __syncthreads();
        sh[t] += add;
        __syncthreads();
    }
    if (t < NB) bsum[t] = (t == 0) ? 0 : sh[t - 1];
}

__global__ __launch_bounds__(256) void scanfinal_kernel(
    const int* __restrict__ deg, const int* __restrict__ bsum,
    int* __restrict__ rowptr, int* __restrict__ cursor, int N)
{
    int b = blockIdx.x, t = threadIdx.x;
    int i = b * 256 + t;
    int v = (i < N) ? deg[i] : 0;
    __shared__ int sh[256];
    sh[t] = v;
    __syncthreads();
    for (int o = 1; o < 256; o <<= 1) {
        int add = (t >= o) ? sh[t - o] : 0;
        __syncthreads();
        sh[t] += add;
        __syncthreads();
    }
    int excl = sh[t] - v;
    if (i < N) {
        int rp = bsum[b] + excl;
        rowptr[i] = rp;
        cursor[i] = rp;
        if (i == N - 1) rowptr[N] = rp + v;
    }
}

__global__ __launch_bounds__(256) void fill_kernel(
    const int* __restrict__ ei, int* __restrict__ cursor, int* __restrict__ col, int E)
{
    int e = blockIdx.x * 256 + threadIdx.x;
    if (e >= E) return;
    int d = ei[E + e];
    int pos = atomicAdd(&cursor[d], 1);
    col[pos] = ei[e];
}

// ================= weight prepack: f32 [128][128] -> packed per-matrix [hi|lo] planes =================
// Matrix m at wPk[m*32768..): 16384 hi then 16384 lo.
// idx = kb*4096 + cf*512 + lane*8 + j : element W[kb*32+(lane>>4)*8+j][cf*16+(lane&15)].
__global__ __launch_bounds__(256) void prepack_kernel(
    const float* __restrict__ W0, const float* __restrict__ W1,
    const float* __restrict__ W2, const float* __restrict__ W3,
    const float* __restrict__ W4, const float* __restrict__ W5,
    ushort* __restrict__ wPk)
{
    int m = blockIdx.y;
    const float* W = (m == 0) ? W0 : (m == 1) ? W1 : (m == 2) ? W2
                   : (m == 3) ? W3 : (m == 4) ? W4 : W5;
    int base = m * 32768;
#pragma unroll
    for (int t = 0; t < 8; ++t) {
        int idx = blockIdx.x * 2048 + t * 256 + threadIdx.x;
        int j = idx & 7, l = (idx >> 3) & 63, cf = (idx >> 9) & 7, kb = idx >> 12;
        int k = kb * 32 + (l >> 4) * 8 + j;
        int n = cf * 16 + (l & 15);
        float v = W[k * 128 + n];
        unsigned u = __float_as_uint(v);
        wPk[base + idx] = (ushort)(u >> 16);
        float r = v - __uint_as_float(u & 0xffff0000u);
        wPk[base + 16384 + idx] = (ushort)(__float_as_uint(r) >> 16);
    }
}

// ================= fused gather + dual MFMA linear + stats (persistent) =================
// Y = agg(X)@Wl + X@Wr + bias, where agg is CSR-gather of (optionally bnrelu'd) X.
// Per 16-row tile: staging thread (srow,sunit) runs the edge loop for its row's
// float4 slice (agg in regs), loads root row, applies BN, splits ONCE to padded
// bf16 hi/lo LDS planes. Compute = ds_read_b128 + MFMA with register-resident W.
template<int BN>
__global__ __launch_bounds__(512, 2) void glin_kernel(
    const float* __restrict__ X, const int* __restrict__ rowptr,
    const int* __restrict__ colIdx, const ushort* __restrict__ wPair,
    const float* __restrict__ bias, const float* __restrict__ bnst,
    float* __restrict__ Y, float* __restrict__ stOut, int nrows)
{
    // planes: [m][hi/lo][16 rows][136 bf16]; m0 = agg (Wl), m1 = root (Wr)
    __shared__ ushort ldsA[2 * 2 * 2176];
    const int tid  = threadIdx.x;
    const int lane = tid & 63;
    const int w    = tid >> 6;
    const int q = lane >> 4, s = lane & 15;

    // W fragments -> registers (once)
    bf16x8 wf[2][4][2];
#pragma unroll
    for (int m = 0; m < 2; ++m)
#pragma unroll
        for (int kb = 0; kb < 4; ++kb) {
            size_t o = (size_t)m * 32768 + (size_t)kb * 4096 + w * 512 + lane * 8;
            wf[m][kb][0] = *(const bf16x8*)(wPair + o);
            wf[m][kb][1] = *(const bf16x8*)(wPair + o + 16384);
        }

    const int srow  = tid >> 5;
    const int sunit = tid & 31;
    float4 bna, bnd;
    if (BN) {
        bna = *(const float4*)(bnst + 256 + sunit * 4);
        bnd = *(const float4*)(bnst + 384 + sunit * 4);
    }

    const int colc = w * 16 + s;
    const float bv = bias[colc];
    float cs = 0.f, cq = 0.f;

    const int NT = (nrows + 15) >> 4;
    const int stride = (int)gridDim.x;
    const int t0 = blockIdx.x;
    const int woff = srow * 136 + sunit * 4;

    auto stage = [&](int t) {
        int row = t * 16 + srow; if (row > nrows - 1) row = nrows - 1;
        float4 root = *(const float4*)(X + (size_t)row * 128 + sunit * 4);
        int beg = rowptr[row], end = rowptr[row + 1];
        float ax = 0.f, ay = 0.f, az = 0.f, aw = 0.f;
        float bx = 0.f, by = 0.f, bz = 0.f, bw = 0.f;
        int e = beg;
        for (; e + 2 <= end; e += 2) {
            int s0 = colIdx[e], s1 = colIdx[e + 1];
            float4 v0 = *(const float4*)(X + (size_t)s0 * 128 + sunit * 4);
            float4 v1 = *(const float4*)(X + (size_t)s1 * 128 + sunit * 4);
            if (BN) { v0 = bnrelu4(v0, bna, bnd); v1 = bnrelu4(v1, bna, bnd); }
            ax += v0.x; ay += v0.y; az += v0.z; aw += v0.w;
            bx += v1.x; by += v1.y; bz += v1.z; bw += v1.w;
        }
        if (e < end) {
            int s0 = colIdx[e];
            float4 v0 = *(const float4*)(X + (size_t)s0 * 128 + sunit * 4);
            if (BN) v0 = bnrelu4(v0, bna, bnd);
            ax += v0.x; ay += v0.y; az += v0.z; aw += v0.w;
        }
        float4 agg = make_float4(ax + bx, ay + by, az + bz, aw + bw);
        if (BN) root = bnrelu4(root, bna, bnd);
        ushort4 h, l;
        split4(agg, h, l);
        *(ushort4*)(ldsA + woff)        = h;
        *(ushort4*)(ldsA + 2176 + woff) = l;
        split4(root, h, l);
        *(ushort4*)(ldsA + 4352 + woff) = h;
        *(ushort4*)(ldsA + 6528 + woff) = l;
    };

    if (t0 < NT) stage(t0);

    for (int t = t0; t < NT; t += stride) {
        __syncthreads();   // staged planes visible

        f32x4 acc = (f32x4){0.f, 0.f, 0.f, 0.f};
#pragma unroll
        for (int m = 0; m < 2; ++m) {
            const ushort* pm = ldsA + m * 4352 + s * 136;
#pragma unroll
            for (int kb = 0; kb < 4; ++kb) {
                bf16x8 ah = *(const bf16x8*)(pm + (kb * 4 + q) * 8);
                bf16x8 al = *(const bf16x8*)(pm + 2176 + (kb * 4 + q) * 8);
                acc = __builtin_amdgcn_mfma_f32_16x16x32_bf16(ah, wf[m][kb][0], acc, 0, 0, 0);
                acc = __builtin_amdgcn_mfma_f32_16x16x32_bf16(al, wf[m][kb][0], acc, 0, 0, 0);
                acc = __builtin_amdgcn_mfma_f32_16x16x32_bf16(ah, wf[m][kb][1], acc, 0, 0, 0);
            }
        }

        int r0 = t * 16 + q * 4;
#pragma unroll
        for (int i = 0; i < 4; ++i) {
            int r = r0 + i;
            if (r < nrows) {
                float y = acc[i] + bv;
                Y[(size_t)r * 128 + colc] = y;
                cs += y; cq += y * y;
            }
        }
        __syncthreads();   // plane reads done
        int tn = t + stride;
        if (tn < NT) stage(tn);
    }

    cs += __shfl_xor(cs, 16); cs += __shfl_xor(cs, 32);
    cq += __shfl_xor(cq, 16); cq += __shfl_xor(cq, 32);
    if (q == 0) {
        atomicAdd(&stOut[colc], cs);
        atomicAdd(&stOut[128 + colc], cq);
    }
}

// ================= fused MLP head: out = relu(relu(bnrelu(X)@W1+b1)@W2+b2)@W3+b3 =================
// Row-local chain fused in one persistent kernel. Per tile: stage bnrelu(X) -> planes;
// MFMA(W1) -> relu -> LDS y-tile; re-split -> planes; MFMA(W2) -> relu -> LDS;
// per-row dot with W3 (shfl-reduce over 32 lanes) -> out. 4 barriers/tile.
__global__ __launch_bounds__(512, 2) void mlp_kernel(
    const float* __restrict__ X, const ushort* __restrict__ w1Pk,
    const ushort* __restrict__ w2Pk, const float* __restrict__ b1,
    const float* __restrict__ b2, const float* __restrict__ W3,
    const float* __restrict__ b3, const float* __restrict__ bnst,
    float* __restrict__ out, int nrows)
{
    __shared__ ushort ldsP[2 * 2176];    // hi/lo planes for current GEMM input
    __shared__ float  ldsY[16 * 132];    // y tile (132-pad)
    const int tid  = threadIdx.x;
    const int lane = tid & 63;
    const int w    = tid >> 6;
    const int q = lane >> 4, s = lane & 15;

    bf16x8 wf1[4][2], wf2[4][2];
#pragma unroll
    for (int kb = 0; kb < 4; ++kb) {
        size_t o = (size_t)kb * 4096 + w * 512 + lane * 8;
        wf1[kb][0] = *(const bf16x8*)(w1Pk + o);
        wf1[kb][1] = *(const bf16x8*)(w1Pk + o + 16384);
        wf2[kb][0] = *(const bf16x8*)(w2Pk + o);
        wf2[kb][1] = *(const bf16x8*)(w2Pk + o + 16384);
    }

    const int srow  = tid >> 5;
    const int sunit = tid & 31;
    float4 bna = *(const float4*)(bnst + 256 + sunit * 4);
    float4 bnd = *(const float4*)(bnst + 384 + sunit * 4);

    float w30[4], w31[4];
#pragma unroll
    for (int j = 0; j < 4; ++j) {
        w30[j] = W3[(sunit * 4 + j) * 2];
        w31[j] = W3[(sunit * 4 + j) * 2 + 1];
    }
    const float b30 = b3[0], b31 = b3[1];

    const int colc = w * 16 + s;
    const float bv1 = b1[colc];
    const float bv2 = b2[colc];

    const int NT = (nrows + 15) >> 4;
    const int stride = (int)gridDim.x;
    const int t0 = blockIdx.x;
    const int woff = srow * 136 + sunit * 4;

    auto stageX = [&](int t) {
        int row = t * 16 + srow; if (row > nrows - 1) row = nrows - 1;
        float4 v = *(const float4*)(X + (size_t)row * 128 + sunit * 4);
        v = bnrelu4(v, bna, bnd);
        ushort4 h, l;
        split4(v, h, l);
        *(ushort4*)(ldsP + woff)        = h;
        *(ushort4*)(ldsP + 2176 + woff) = l;
    };

    auto gemm = [&](const bf16x8 (&wf)[4][2]) {
        f32x4 acc = (f32x4){0.f, 0.f, 0.f, 0.f};
        const ushort* pm = ldsP + s * 136;
#pragma unroll
        for (int kb = 0; kb < 4; ++kb) {
            bf16x8 ah = *(const bf16x8*)(pm + (kb * 4 + q) * 8);
            bf16x8 al = *(const bf16x8*)(pm + 2176 + (kb * 4 + q) * 8);
            acc = __builtin_amdgcn_mfma_f32_16x16x32_bf16(ah, wf[kb][0], acc, 0, 0, 0);
            acc = __builtin_amdgcn_mfma_f32_16x16x32_bf16(al, wf[kb][0], acc, 0, 0, 0);
            acc = __builtin_amdgcn_mfma_f32_16x16x32_bf16(ah, wf[kb][1], acc, 0, 0, 0);
        }
        return acc;
    };

    if (t0 < NT) stageX(t0);

    for (int t = t0; t < NT; t += stride) {
        __syncthreads();                         // (a) planes(X) ready; prev dot's ldsY reads done

        f32x4 acc = gemm(wf1);
#pragma unroll
        for (int i = 0; i < 4; ++i)
            ldsY[(q * 4 + i) * 132 + colc] = fmaxf(acc[i] + bv1, 0.f);
        __syncthreads();                         // (c) y1 ready; planes(X) reads done

        {   // re-split y1 -> planes
            float4 yv = *(const float4*)&ldsY[srow * 132 + sunit * 4];
            ushort4 h, l;
            split4(yv, h, l);
            *(ushort4*)(ldsP + woff)        = h;
            *(ushort4*)(ldsP + 2176 + woff) = l;
        }
        __syncthreads();                         // (d) planes(y1) ready; y1 reads done

        acc = gemm(wf2);
#pragma unroll
        for (int i = 0; i < 4; ++i)
            ldsY[(q * 4 + i) * 132 + colc] = fmaxf(acc[i] + bv2, 0.f);
        __syncthreads();                         // (e) y2 ready; planes(y1) reads done

        {   // per-row projection to DOUT=2
            float4 yv = *(const float4*)&ldsY[srow * 132 + sunit * 4];
            float p0 = yv.x * w30[0] + yv.y * w30[1] + yv.z * w30[2] + yv.w * w30[3];
            float p1 = yv.x * w31[0] + yv.y * w31[1] + yv.z * w31[2] + yv.w * w31[3];
#pragma unroll
            for (int o = 1; o < 32; o <<= 1) {
                p0 += __shfl_xor(p0, o);
                p1 += __shfl_xor(p1, o);
            }
            int row = t * 16 + srow;
            if (sunit == 0 && row < nrows)
                *(float2*)(out + (size_t)row * 2) = make_float2(p0 + b30, p1 + b31);
        }
        int tn = t + stride;
        if (tn < NT) stageX(tn);                 // writes ldsP (reads done at (e))
    }
}

// ================= BN finalize: st -> per-column affine (a, d) =================
__global__ void finalize_kernel(float* st, const float* __restrict__ g,
                                const float* __restrict__ be, float inv_n)
{
    int c = threadIdx.x;
    float mu = st[c] * inv_n;
    float var = st[128 + c] * inv_n - mu * mu;
    float rs = rsqrtf(var + EPS);
    float a = g[c] * rs;
    st[256 + c] = a;
    st[384 + c] = be[c] - mu * a;
}

extern "C" void kernel_launch(void* const* d_in, const int* in_sizes, int n_in,
                              void* d_out, int out_size, void* d_ws, size_t ws_size,
                              hipStream_t stream) {
    const float* x   = (const float*)d_in[0];
    const int*   ei  = (const int*)d_in[1];
    const float* Wl0 = (const float*)d_in[2];
    const float* bl0 = (const float*)d_in[3];
    const float* Wr0 = (const float*)d_in[4];
    const float* Wl1 = (const float*)d_in[5];
    const float* bl1 = (const float*)d_in[6];
    const float* Wr1 = (const float*)d_in[7];
    const float* g0  = (const float*)d_in[8];
    const float* be0 = (const float*)d_in[9];
    const float* g1  = (const float*)d_in[10];
    const float* be1 = (const float*)d_in[11];
    const float* W1  = (const float*)d_in[12];
    const float* b1  = (const float*)d_in[13];
    const float* W2  = (const float*)d_in[14];
    const float* b2  = (const float*)d_in[15];
    const float* W3  = (const float*)d_in[16];
    const float* b3  = (const float*)d_in[17];
    float* out = (float*)d_out;

    const int N = in_sizes[0] / 128;
    const int E = in_sizes[1] / 2;

    // workspace layout
    float* A   = (float*)d_ws;                   // [N,128]
    float* B   = A + (size_t)N * 128;            // [N,128]
    float* st0 = B + (size_t)N * 128;            // 512 floats
    float* st1 = st0 + 512;                      // 512 floats
    ushort* wPk = (ushort*)(st1 + 512);          // 6 * 32768
    int* deg    = (int*)(wPk + 6 * 32768);       // N
    int* rowptr = deg + N;                       // N+1
    int* cursor = rowptr + N + 1;                // N
    int* col    = cursor + N;                    // E
    int* bsum   = col + E;                       // <=512

    const int edgeGrid = (E + 255) / 256;
    const int nodeGrid = (N + 255) / 256;
    const float inv_n = 1.0f / (float)N;

    // matrix slots: 0=Wl0 1=Wr0 2=Wl1 3=Wr1 4=W1 5=W2 (dual pairs adjacent)
    prepack_kernel<<<dim3(8, 6), 256, 0, stream>>>(Wl0, Wr0, Wl1, Wr1, W1, W2, wPk);

    // ----- CSR build -----
    hipMemsetAsync(deg, 0, (size_t)N * sizeof(int), stream);
    hist_kernel<<<edgeGrid, 256, 0, stream>>>(ei, deg, E);
    blocksum_kernel<<<nodeGrid, 256, 0, stream>>>(deg, bsum, N);
    scanb_kernel<<<1, 512, 0, stream>>>(bsum, nodeGrid);
    scanfinal_kernel<<<nodeGrid, 256, 0, stream>>>(deg, bsum, rowptr, cursor, N);
    fill_kernel<<<edgeGrid, 256, 0, stream>>>(ei, cursor, col, E);

    // ----- layer 0: A = agg(x)@Wl0 + x@Wr0 + bl0 (fused gather+lin), stats st0 -----
    hipMemsetAsync(st0, 0, 256 * sizeof(float), stream);
    glin_kernel<0><<<512, 512, 0, stream>>>(
        x, rowptr, col, wPk, bl0, nullptr, A, st0, N);
    finalize_kernel<<<1, 128, 0, stream>>>(st0, g0, be0, inv_n);

    // ----- layer 1: B = agg(bn0(A))@Wl1 + bn0(A)@Wr1 + bl1, stats st1 -----
    hipMemsetAsync(st1, 0, 256 * sizeof(float), stream);
    glin_kernel<1><<<512, 512, 0, stream>>>(
        A, rowptr, col, wPk + 2 * 32768, bl1, st0, B, st1, N);
    finalize_kernel<<<1, 128, 0, stream>>>(st1, g1, be1, inv_n);

    // ----- fused MLP head + projection -----
    mlp_kernel<<<512, 512, 0, stream>>>(
        B, wPk + 4 * 32768, wPk + 5 * 32768, b1, b2, W3, b3, st1, out, N);
}